// Round 1
// baseline (437.271 us; speedup 1.0000x reference)
//
#include <hip/hip_runtime.h>

// Problem constants (fixed by the reference): B=256, N=2048, D=128, ANCHOR=0
#define B_SZ    256
#define N_NODES 2048
#define D_DIM   128
#define NROW_TOT (B_SZ * N_NODES)   // 524288

typedef __attribute__((ext_vector_type(8))) short short8;   // 8 bf16 = 4 VGPRs (MFMA A/B frag)
typedef __attribute__((ext_vector_type(4))) float f32x4;    // MFMA C/D frag

// ---- workspace layout (bytes) ----
#define WS_W1BF   0          // 128*256 bf16 = 65536
#define WS_COUNT  65536      // 256 * 4
#define WS_OFF    66560      // 256 * 4
#define WS_CURSOR 67584      // 256 * 64  (one counter per 64B line)
#define WS_ACC    83968      // 256*128*4 = 131072
#define WS_P      215040     // 524288 * 4
#define WS_NEEDED (WS_P + NROW_TOT * 4)

// RNE fp32->bf16 pack of two floats into one uint (lo = first)
__device__ __forceinline__ unsigned pk2(float x, float y) {
    unsigned a = __float_as_uint(x), b = __float_as_uint(y);
    a += 0x7fffu + ((a >> 16) & 1u);
    b += 0x7fffu + ((b >> 16) & 1u);
    return (a >> 16) | (b & 0xffff0000u);
}

// ---- W1 (128x256 fp32, row-major [d][k]) -> bf16 same layout ----
__global__ void k_prep_w1(const float* __restrict__ W1, unsigned* __restrict__ w1bf) {
    int i = blockIdx.x * 256 + threadIdx.x;           // 16384 float2 pairs
    float2 f = ((const float2*)W1)[i];
    w1bf[i] = pk2(f.x, f.y);
}

// ---- histogram of batch_idx over non-anchor rows ----
__global__ void k_hist(const int* __restrict__ bidx, int* __restrict__ count) {
    __shared__ int lh[256];
    int t = threadIdx.x;
    lh[t] = 0;
    __syncthreads();
    int base = blockIdx.x * 1024 + t * 4;
    int4 v = ((const int4*)bidx)[blockIdx.x * 256 + t];
    if (((base + 0) & 2047) != 0) atomicAdd(&lh[v.x], 1);
    if (((base + 1) & 2047) != 0) atomicAdd(&lh[v.y], 1);
    if (((base + 2) & 2047) != 0) atomicAdd(&lh[v.z], 1);
    if (((base + 3) & 2047) != 0) atomicAdd(&lh[v.w], 1);
    __syncthreads();
    if (lh[t]) atomicAdd(&count[t], lh[t]);
}

// ---- exclusive prefix sum of counts; init cursors ----
__global__ void k_scan(const int* __restrict__ count, int* __restrict__ off,
                       int* __restrict__ cursor) {
    __shared__ int sv[256];
    int t = threadIdx.x;
    sv[t] = count[t];
    __syncthreads();
    for (int o = 1; o < 256; o <<= 1) {
        int v = (t >= o) ? sv[t - o] : 0;
        __syncthreads();
        sv[t] += v;
        __syncthreads();
    }
    int ex = sv[t] - count[t];
    off[t] = ex;
    cursor[t * 16] = ex;
}

// ---- scatter row ids into per-segment buckets (block-aggregated atomics) ----
__global__ void k_scatter(const int* __restrict__ bidx, int* __restrict__ cursor,
                          int* __restrict__ P) {
    __shared__ int lh[256];
    __shared__ int sbase[256];
    int t = threadIdx.x;
    lh[t] = 0;
    __syncthreads();
    int base = blockIdx.x * 1024 + t * 4;
    int4 v = ((const int4*)bidx)[blockIdx.x * 256 + t];
    int p0 = -1, p1 = -1, p2 = -1, p3 = -1;
    if (((base + 0) & 2047) != 0) p0 = atomicAdd(&lh[v.x], 1);
    if (((base + 1) & 2047) != 0) p1 = atomicAdd(&lh[v.y], 1);
    if (((base + 2) & 2047) != 0) p2 = atomicAdd(&lh[v.z], 1);
    if (((base + 3) & 2047) != 0) p3 = atomicAdd(&lh[v.w], 1);
    __syncthreads();
    if (lh[t]) sbase[t] = atomicAdd(&cursor[t * 16], lh[t]);
    __syncthreads();
    if (p0 >= 0) P[sbase[v.x] + p0] = base + 0;
    if (p1 >= 0) P[sbase[v.y] + p1] = base + 1;
    if (p2 >= 0) P[sbase[v.z] + p2] = base + 2;
    if (p3 >= 0) P[sbase[v.w] + p3] = base + 3;
}

// ---- main: per-segment gather + bf16 MFMA GEMM (K=256: [target|emb]) + row-sum ----
#define CHUNK   64
#define ESTRIDE 528   // 512B (256 bf16) + 16B pad -> conflict-free b128 access

__global__ __launch_bounds__(1024) void k_main(
    const float* __restrict__ embs, const float* __restrict__ b1,
    const short* __restrict__ w1bf, const int* __restrict__ P,
    const int* __restrict__ off, const int* __restrict__ count,
    float* __restrict__ ACC)
{
    __shared__ char  estage[CHUNK * ESTRIDE];   // 33792 B
    __shared__ float segacc[D_DIM];

    int tid = threadIdx.x;
    int s   = blockIdx.x;
    int cnt = count[s];
    int base = off[s];

    if (tid < D_DIM) segacc[tid] = 0.f;

    int lane = tid & 63;
    int wid  = tid >> 6;       // 0..15
    int rt   = wid & 3;        // row-tile (16 rows each)
    int cg   = wid >> 2;       // col-group (32 cols each)
    int q    = lane >> 4;      // quad 0..3
    int i15  = lane & 15;

    // B fragments: W1[n][k], n = cg*32 + ct*16 + i15, k = kt*32 + q*8 .. +8
    short8 bfrag[8][2];
#pragma unroll
    for (int kt = 0; kt < 8; kt++)
#pragma unroll
        for (int ct = 0; ct < 2; ct++) {
            int n = cg * 32 + ct * 16 + i15;
            bfrag[kt][ct] = *(const short8*)(w1bf + n * 256 + kt * 32 + q * 8);
        }
    float b1c0 = b1[cg * 32 + i15];
    float b1c1 = b1[cg * 32 + 16 + i15];
    float asum0 = 0.f, asum1 = 0.f;

    int srow = tid >> 4;   // 0..63: staged row
    int part = tid & 15;   // 16 floats (k part*16..+16) per thread
    __syncthreads();       // segacc zero visible

    int nchunk = (cnt + CHUNK - 1) >> 6;
    for (int c = 0; c < nchunk; c++) {
        // -------- stage 64 rows: k[0..127]=target(b), k[128..255]=emb row ------
        int rl = c * 64 + srow;
        int gr = base + (rl < cnt ? rl : cnt - 1);
        int ridx = P[gr];
        int b = ridx >> 11;
        const float4* src;
        if (part < 8) src = (const float4*)(embs + (b << 11) * D_DIM) + part * 4;
        else          src = (const float4*)(embs + ridx * D_DIM) + (part - 8) * 4;
        float4 f0 = src[0], f1 = src[1], f2 = src[2], f3 = src[3];
        unsigned u0 = pk2(f0.x, f0.y), u1 = pk2(f0.z, f0.w);
        unsigned u2 = pk2(f1.x, f1.y), u3 = pk2(f1.z, f1.w);
        unsigned u4 = pk2(f2.x, f2.y), u5 = pk2(f2.z, f2.w);
        unsigned u6 = pk2(f3.x, f3.y), u7 = pk2(f3.z, f3.w);
        uint4* dst = (uint4*)(estage + srow * ESTRIDE + part * 32);
        dst[0] = make_uint4(u0, u1, u2, u3);
        dst[1] = make_uint4(u4, u5, u6, u7);
        __syncthreads();

        // -------- MFMA: 16 rows x 32 cols per wave, K=256 ----------------------
        f32x4 m0 = {0.f, 0.f, 0.f, 0.f}, m1 = {0.f, 0.f, 0.f, 0.f};
        const char* arow = estage + (rt * 16 + i15) * ESTRIDE + q * 16;
#pragma unroll
        for (int kt = 0; kt < 8; kt++) {
            short8 a = *(const short8*)(arow + kt * 64);
            m0 = __builtin_amdgcn_mfma_f32_16x16x32_bf16(a, bfrag[kt][0], m0, 0, 0, 0);
            m1 = __builtin_amdgcn_mfma_f32_16x16x32_bf16(a, bfrag[kt][1], m1, 0, 0, 0);
        }
        // epilogue: h = relu(acc + b1), sum over valid rows (D row = q*4+j)
        int rbase = c * 64 + rt * 16 + q * 4;
#pragma unroll
        for (int j = 0; j < 4; j++) {
            if (rbase + j < cnt) {
                asum0 += fmaxf(m0[j] + b1c0, 0.f);
                asum1 += fmaxf(m1[j] + b1c1, 0.f);
            }
        }
        __syncthreads();   // before next chunk overwrites estage
    }

    // reduce across quads (same col in lanes l, l^16, l^32, l^48)
    asum0 += __shfl_xor(asum0, 16, 64);
    asum0 += __shfl_xor(asum0, 32, 64);
    asum1 += __shfl_xor(asum1, 16, 64);
    asum1 += __shfl_xor(asum1, 32, 64);
    if (lane < 16) {
        atomicAdd(&segacc[cg * 32 + lane],      asum0);
        atomicAdd(&segacc[cg * 32 + 16 + lane], asum1);
    }
    __syncthreads();
    if (tid < D_DIM) ACC[s * D_DIM + tid] = segacc[tid];
}

// ---- out[s][d] = sum_k ACC[s][k] * W2[d][k] + cnt[s]*b2[d] ----
__global__ void k_out(const float* __restrict__ ACC, const float* __restrict__ W2,
                      const float* __restrict__ b2, const int* __restrict__ count,
                      float* __restrict__ out) {
    __shared__ float a[D_DIM];
    int s = blockIdx.x, d = threadIdx.x;
    a[d] = ACC[s * D_DIM + d];
    __syncthreads();
    float sum = (float)count[s] * b2[d];
    const float4* w = (const float4*)(W2 + d * D_DIM);
#pragma unroll
    for (int k = 0; k < 32; k++) {
        float4 wv = w[k];
        sum += a[4 * k + 0] * wv.x + a[4 * k + 1] * wv.y
             + a[4 * k + 2] * wv.z + a[4 * k + 3] * wv.w;
    }
    out[s * D_DIM + d] = sum;
}

extern "C" void kernel_launch(void* const* d_in, const int* in_sizes, int n_in,
                              void* d_out, int out_size, void* d_ws, size_t ws_size,
                              hipStream_t stream) {
    const float* embs = (const float*)d_in[0];
    const float* W1   = (const float*)d_in[1];
    const float* b1   = (const float*)d_in[2];
    const float* W2   = (const float*)d_in[3];
    const float* b2   = (const float*)d_in[4];
    const int*   bidx = (const int*)d_in[5];

    char* ws = (char*)d_ws;
    unsigned* w1bf_u = (unsigned*)(ws + WS_W1BF);
    short*    w1bf   = (short*)(ws + WS_W1BF);
    int*   count  = (int*)(ws + WS_COUNT);
    int*   off    = (int*)(ws + WS_OFF);
    int*   cursor = (int*)(ws + WS_CURSOR);
    float* ACC    = (float*)(ws + WS_ACC);
    int*   P      = (int*)(ws + WS_P);

    hipMemsetAsync(count, 0, 256 * sizeof(int), stream);
    k_prep_w1<<<64, 256, 0, stream>>>(W1, w1bf_u);
    k_hist<<<512, 256, 0, stream>>>(bidx, count);
    k_scan<<<1, 256, 0, stream>>>(count, off, cursor);
    k_scatter<<<512, 256, 0, stream>>>(bidx, cursor, P);
    k_main<<<256, 1024, 0, stream>>>(embs, b1, w1bf, P, off, count, ACC);
    k_out<<<256, 128, 0, stream>>>(ACC, W2, b2, count, (float*)d_out);
}